// Round 2
// baseline (252.084 us; speedup 1.0000x reference)
//
#include <hip/hip_runtime.h>
#include <math.h>

#define N_NODES 100000
#define NG 100
#define N_PER 1000
#define N_EDGES 3200000
#define EPG 32000
#define EPG4 8000
#define EPGP 35008
#define K_TOP 800
#define F_IN 128
#define F_MID 16
#define F_OUT 256
#define SENT 1000
#define NCH 8
#define CHN 128

typedef __attribute__((ext_vector_type(8))) short short8;
typedef __attribute__((ext_vector_type(4))) float floatx4;

__device__ __forceinline__ unsigned short f2bf(float x) {
    union { float f; unsigned int u; } c; c.f = x;
    unsigned int u = c.u;
    u = u + 0x7FFF + ((u >> 16) & 1);
    return (unsigned short)(u >> 16);
}
__device__ __forceinline__ void add4(float4& a, const float4 b) {
    a.x += b.x; a.y += b.y; a.z += b.z; a.w += b.w;
}
// order-preserving float->uint key (ascending)
__device__ __forceinline__ unsigned int fkey(float f) {
    unsigned int u = __float_as_uint(f);
    return (u & 0x80000000u) ? ~u : (u | 0x80000000u);
}

// ============ kernel 1: CSR blocks (1024 thr) + GEMM1 tiles (64 nodes) ============
__global__ __launch_bounds__(1024) void k_front(const float* __restrict__ x,
    const float* __restrict__ W1, const int* __restrict__ ei,
    unsigned short* __restrict__ csr, int* __restrict__ crG,
    float* __restrict__ dis1G, float* __restrict__ xw1)
{
    int b = blockIdx.x, t = threadIdx.x;
    if (b < NG) {
        __shared__ int cnts[N_PER];
        __shared__ int cur[N_PER];
        __shared__ int rs[N_PER];
        __shared__ int scan[1024];
        int g = b, ebase = g * EPG, nbase = g * N_PER;
        if (b == 0 && t < F_MID) xw1[(size_t)N_NODES * F_MID + t] = 0.f; // sentinel row
        const int4* dst4 = (const int4*)(ei + N_EDGES + ebase);
        const int4* src4 = (const int4*)(ei + ebase);
        int4 dreg[8], sreg[8];
        int ni = 0;
        for (int i = t; i < EPG4; i += 1024) { dreg[ni] = dst4[i]; sreg[ni] = src4[i]; ni++; }
        if (t < N_PER) { cnts[t] = 0; cur[t] = 0; }
        __syncthreads();
        for (int i = 0; i < ni; i++) {
            atomicAdd(&cnts[dreg[i].x - nbase], 1);
            atomicAdd(&cnts[dreg[i].y - nbase], 1);
            atomicAdd(&cnts[dreg[i].z - nbase], 1);
            atomicAdd(&cnts[dreg[i].w - nbase], 1);
        }
        __syncthreads();
        int c = (t < N_PER) ? cnts[t] : 0;
        int c4 = (c + 3) & ~3;
        scan[t] = c4;
        __syncthreads();
        for (int dd = 1; dd < 1024; dd <<= 1) {
            int v = (t >= dd) ? scan[t - dd] : 0;
            __syncthreads();
            scan[t] += v;
            __syncthreads();
        }
        int exc = scan[t] - c4;
        unsigned short* cg = csr + (size_t)g * EPGP;
        if (t < N_PER) {
            rs[t] = exc;
            crG[nbase + t] = (c << 16) | exc;     // pack cnt|rs (both < 2^16)
            dis1G[nbase + t] = rsqrtf((float)c + 1.0f);
            for (int q = c; q < c4; q++) cg[exc + q] = (unsigned short)SENT;
        }
        __syncthreads();
        for (int i = 0; i < ni; i++) {
            int dl, p;
            dl = dreg[i].x - nbase; p = rs[dl] + atomicAdd(&cur[dl], 1); cg[p] = (unsigned short)(sreg[i].x - nbase);
            dl = dreg[i].y - nbase; p = rs[dl] + atomicAdd(&cur[dl], 1); cg[p] = (unsigned short)(sreg[i].y - nbase);
            dl = dreg[i].z - nbase; p = rs[dl] + atomicAdd(&cur[dl], 1); cg[p] = (unsigned short)(sreg[i].z - nbase);
            dl = dreg[i].w - nbase; p = rs[dl] + atomicAdd(&cur[dl], 1); cg[p] = (unsigned short)(sreg[i].w - nbase);
        }
    } else {
        __shared__ float xs[64 * 132];
        __shared__ float wsm[F_IN * F_MID];
        long tile = b - NG;
        long n0 = tile * 64;
        int nmax = (int)((N_NODES - n0 < 64) ? (N_NODES - n0) : 64);
        const float* xp = x + n0 * F_IN;
        for (int i = t; i < nmax * F_IN; i += 1024) {
            int n = i >> 7, k = i & 127;
            xs[n * 132 + k] = xp[i];
        }
        for (int i = t; i < F_IN * F_MID; i += 1024) wsm[i] = W1[i];
        __syncthreads();
        int node = t >> 4, j = t & 15;
        if (node < nmax) {
            const float* xr = xs + node * 132;
            float acc = 0.f;
#pragma unroll 16
            for (int k = 0; k < F_IN; k++) acc += xr[k] * wsm[k * F_MID + j];
            xw1[(n0 + node) * F_MID + j] = acc;
        }
    }
}

// ============ kernel 2: conv1 + readout scalars, grid-parallel (800 blocks) ============
__global__ __launch_bounds__(512) void k_conv1(const unsigned short* __restrict__ csr,
    const int* __restrict__ crG,
    const float* __restrict__ dis1G, const float* __restrict__ xw1,
    const float* __restrict__ b1, const float* __restrict__ w_rel,
    const float* __restrict__ w_root,
    float* __restrict__ hG, float* __restrict__ hwG, float* __restrict__ hroG)
{
    __shared__ float dis1l[N_PER + 1];
    int t = threadIdx.x, b = blockIdx.x;
    int g = b % NG, chunk = b / NG;          // chunks of a graph land on only 2 XCDs
    int nbase = g * N_PER;
    const unsigned short* cg = csr + (size_t)g * EPGP;
    if (b == 0 && t < F_MID) hG[(size_t)N_NODES * F_MID + t] = 0.f;  // sentinel row
    for (int i = t; i < N_PER; i += 512) dis1l[i] = dis1G[nbase + i];
    if (t == 0) dis1l[SENT] = 0.f;
    __syncthreads();

    int grp = t >> 2, l = t & 3;
    int n = chunk * CHN + grp;
    if (n >= N_PER) return;
    int cr = crG[nbase + n];
    int c4 = ((cr >> 16) + 3) & ~3;
    const unsigned short* cp = cg + (cr & 0xFFFF);
    float4 a0 = {0,0,0,0}, a1 = a0, a2 = a0, a3 = a0;
    for (int k = 0; k < c4; k += 4) {
        uint2 wv = *(const uint2*)(cp + k);
        int s0 = wv.x & 0xFFFF, s1 = wv.x >> 16, s2 = wv.y & 0xFFFF, s3 = wv.y >> 16;
        float4 v0 = *(const float4*)(xw1 + ((size_t)(nbase + s0) << 4) + 4 * l);
        float4 v1 = *(const float4*)(xw1 + ((size_t)(nbase + s1) << 4) + 4 * l);
        float4 v2 = *(const float4*)(xw1 + ((size_t)(nbase + s2) << 4) + 4 * l);
        float4 v3 = *(const float4*)(xw1 + ((size_t)(nbase + s3) << 4) + 4 * l);
        float w0 = dis1l[s0], w1 = dis1l[s1], w2 = dis1l[s2], w3 = dis1l[s3];
        a0.x = fmaf(v0.x, w0, a0.x); a0.y = fmaf(v0.y, w0, a0.y); a0.z = fmaf(v0.z, w0, a0.z); a0.w = fmaf(v0.w, w0, a0.w);
        a1.x = fmaf(v1.x, w1, a1.x); a1.y = fmaf(v1.y, w1, a1.y); a1.z = fmaf(v1.z, w1, a1.z); a1.w = fmaf(v1.w, w1, a1.w);
        a2.x = fmaf(v2.x, w2, a2.x); a2.y = fmaf(v2.y, w2, a2.y); a2.z = fmaf(v2.z, w2, a2.z); a2.w = fmaf(v2.w, w2, a2.w);
        a3.x = fmaf(v3.x, w3, a3.x); a3.y = fmaf(v3.y, w3, a3.y); a3.z = fmaf(v3.z, w3, a3.z); a3.w = fmaf(v3.w, w3, a3.w);
    }
    add4(a0, a1); add4(a2, a3); add4(a0, a2);
    float dn = dis1l[n];
    float4 sfr = *(const float4*)(xw1 + ((size_t)(nbase + n) << 4) + 4 * l);
    float4 b14 = *(const float4*)(b1 + 4 * l);
    float4 hv;
    hv.x = fmaxf(fmaf(dn, fmaf(sfr.x, dn, a0.x), b14.x), 0.f);
    hv.y = fmaxf(fmaf(dn, fmaf(sfr.y, dn, a0.y), b14.y), 0.f);
    hv.z = fmaxf(fmaf(dn, fmaf(sfr.z, dn, a0.z), b14.z), 0.f);
    hv.w = fmaxf(fmaf(dn, fmaf(sfr.w, dn, a0.w), b14.w), 0.f);
    *(float4*)(hG + ((size_t)(nbase + n) << 4) + 4 * l) = hv;

    float4 wr4 = *(const float4*)(w_rel + 4 * l);
    float4 wo4 = *(const float4*)(w_root + 4 * l);
    float p1 = hv.x * wr4.x + hv.y * wr4.y + hv.z * wr4.z + hv.w * wr4.w;
    float p2 = hv.x * wo4.x + hv.y * wo4.y + hv.z * wo4.z + hv.w * wo4.w;
    p1 += __shfl_xor(p1, 1); p1 += __shfl_xor(p1, 2);
    p2 += __shfl_xor(p2, 1); p2 += __shfl_xor(p2, 2);
    if (l == 0) { hwG[nbase + n] = p1; hroG[nbase + n] = p2; }
}

// ============ kernel 3: score + top-k + mask + deg2/wsrc (per graph) ============
__global__ __launch_bounds__(1024) void k_mid(const unsigned short* __restrict__ csr,
    const int* __restrict__ crG,
    const float* __restrict__ hwG, const float* __restrict__ hroG,
    const float* __restrict__ b_rel,
    float* __restrict__ mskG, float* __restrict__ dis2G, float* __restrict__ wsrcG,
    float* __restrict__ out)
{
    __shared__ float hwl[N_PER + 1];
    __shared__ float sc[N_PER];
    __shared__ float msk[N_PER + 1];
    __shared__ int cntl[N_PER];
    __shared__ int rsl[N_PER];
    __shared__ int hist[1024];
    __shared__ int sh_b1, sh_r1, sh_b2, sh_r2, sh_len, sh_cntgt;
    __shared__ float sh_thr;

    int t = threadIdx.x, g = blockIdx.x;
    int nbase = g * N_PER;
    const unsigned short* cg = csr + (size_t)g * EPGP;
    int grp = t >> 2, l = t & 3;

    if (t < N_PER) {
        int cr = crG[nbase + t];
        cntl[t] = cr >> 16; rsl[t] = cr & 0xFFFF;
        hwl[t] = hwG[nbase + t];
    }
    if (t == 0) { sh_cntgt = 0; sh_len = 0; hwl[SENT] = 0.f; }
    if (t < F_OUT) out[g * F_OUT + t] = 0.f;   // zero for conv2 atomics
    float brel = b_rel[0];
    __syncthreads();

    // ---- score: scalar gather of hw over neighbors ----
#pragma unroll
    for (int rr = 0; rr < 4; rr++) {
        int n = grp + 256 * rr;
        if (n < N_PER) {
            int c4 = (cntl[n] + 3) & ~3;
            const unsigned short* cp = cg + rsl[n];
            float sm = 0.f;
            for (int k = 0; k < c4; k += 4) {
                uint2 wv = *(const uint2*)(cp + k);
                int s = (l == 0) ? (int)(wv.x & 0xFFFF) : (l == 1) ? (int)(wv.x >> 16)
                      : (l == 2) ? (int)(wv.y & 0xFFFF) : (int)(wv.y >> 16);
                sm += hwl[s];
            }
            sm += __shfl_xor(sm, 1); sm += __shfl_xor(sm, 2);
            if (l == 0) sc[n] = tanhf(sm + hroG[nbase + n] + brel);
        }
    }
    __syncthreads();

    // ---- top-K threshold via 2-level radix histogram (exact) ----
    unsigned int mykey = (t < N_PER) ? fkey(sc[t]) : 0u;
    hist[t] = 0;
    __syncthreads();
    if (t < N_PER) atomicAdd(&hist[mykey >> 22], 1);
    __syncthreads();
    {   // suffix-sum via reversed Hillis-Steele
        int v0 = hist[t]; __syncthreads();
        hist[1023 - t] = v0; __syncthreads();
        for (int dd = 1; dd < 1024; dd <<= 1) {
            int v = (t >= dd) ? hist[t - dd] : 0;
            __syncthreads(); hist[t] += v; __syncthreads();
        }
        int Sb = hist[1023 - t];
        int Snext = (t == 1023) ? 0 : hist[1022 - t];
        if (Sb >= K_TOP && Snext < K_TOP) { sh_b1 = t; sh_r1 = K_TOP - Snext; }
    }
    __syncthreads();
    int b1v = sh_b1, r1 = sh_r1;
    hist[t] = 0;
    __syncthreads();
    if (t < N_PER && (int)(mykey >> 22) == b1v) atomicAdd(&hist[(mykey >> 12) & 1023], 1);
    __syncthreads();
    {
        int v0 = hist[t]; __syncthreads();
        hist[1023 - t] = v0; __syncthreads();
        for (int dd = 1; dd < 1024; dd <<= 1) {
            int v = (t >= dd) ? hist[t - dd] : 0;
            __syncthreads(); hist[t] += v; __syncthreads();
        }
        int Sb = hist[1023 - t];
        int Snext = (t == 1023) ? 0 : hist[1022 - t];
        if (Sb >= r1 && Snext < r1) { sh_b2 = t; sh_r2 = r1 - Snext; }
    }
    __syncthreads();
    unsigned int pref = ((unsigned int)b1v << 10) | (unsigned int)sh_b2;
    int r2 = sh_r2;
    __syncthreads();
    if (t < N_PER && (mykey >> 12) == pref) { int p = atomicAdd(&sh_len, 1); hist[p] = (int)mykey; }
    __syncthreads();
    {
        int L = sh_len;
        if (t < L) {
            unsigned int k0 = (unsigned int)hist[t];
            int gcnt = 0, ecnt = 0;
            for (int q2 = 0; q2 < L; q2++) {
                unsigned int kq = (unsigned int)hist[q2];
                gcnt += (kq > k0); ecnt += (kq == k0);
            }
            if (gcnt < r2 && r2 <= gcnt + ecnt)
                sh_thr = __uint_as_float((k0 & 0x80000000u) ? (k0 & 0x7FFFFFFFu) : ~k0);
        }
    }
    __syncthreads();
    float thr = sh_thr;

    // ---- mask (ties: lowest index first, top_k semantics) ----
    {
        bool pred = (t < N_PER) && (sc[t] > thr);
        unsigned long long bal = __ballot(pred);
        if ((t & 63) == 0) atomicAdd(&sh_cntgt, (int)__popcll(bal));
    }
    __syncthreads();
    {
        int need = K_TOP - sh_cntgt;
        if (t < N_PER) {
            float v = sc[t];
            float mm;
            if (v > thr) mm = 1.f;
            else if (v < thr) mm = 0.f;
            else {
                int r = 0;
                for (int q2 = 0; q2 < t; q2++) if (sc[q2] == thr) r++;
                mm = (r < need) ? 1.f : 0.f;
            }
            msk[t] = mm;
        }
        if (t == 0) msk[SENT] = 0.f;
    }
    __syncthreads();

    // ---- deg2 / dis2 / wsrc (scalar mask gather) ----
#pragma unroll
    for (int rr = 0; rr < 4; rr++) {
        int n = grp + 256 * rr;
        if (n < N_PER) {
            int c4 = (cntl[n] + 3) & ~3;
            const unsigned short* cp = cg + rsl[n];
            float sm = 0.f;
            for (int k = 0; k < c4; k += 4) {
                uint2 wv = *(const uint2*)(cp + k);
                int s = (l == 0) ? (int)(wv.x & 0xFFFF) : (l == 1) ? (int)(wv.x >> 16)
                      : (l == 2) ? (int)(wv.y & 0xFFFF) : (int)(wv.y >> 16);
                sm += msk[s];
            }
            sm += __shfl_xor(sm, 1); sm += __shfl_xor(sm, 2);
            if (l == 0) {
                float d2 = msk[n] * (sm + 1.f);
                float di = (d2 > 0.f) ? rsqrtf(d2) : 0.f;
                mskG[nbase + n] = msk[n];
                dis2G[nbase + n] = di;
                wsrcG[nbase + n] = sc[n] * msk[n] * di;
            }
        }
    }
}

// ============ kernel 4: conv2 gather + MFMA + masked mean-pool (800 blocks) ============
__global__ __launch_bounds__(512) void k_conv2(const unsigned short* __restrict__ csr,
    const int* __restrict__ crG,
    const float* __restrict__ hG, const float* __restrict__ wsrcG,
    const float* __restrict__ dis2G, const float* __restrict__ mskG,
    const float* __restrict__ W2, const float* __restrict__ b2,
    float* __restrict__ out)
{
    __shared__ float wsrcl[N_PER + 1];
    __shared__ __align__(16) unsigned short fbf[CHN * F_MID];
    __shared__ __align__(16) unsigned short w2t[F_OUT * F_MID];
    __shared__ float mskl[CHN];
    int t = threadIdx.x, b = blockIdx.x;
    int g = b % NG, chunk = b / NG;
    int nbase = g * N_PER, n0 = chunk * CHN;
    const unsigned short* cg = csr + (size_t)g * EPGP;

    for (int i = t; i < N_PER; i += 512) wsrcl[i] = wsrcG[nbase + i];
    if (t == 0) wsrcl[SENT] = 0.f;
    for (int i = t; i < F_OUT * F_MID; i += 512) {
        int f = i >> 4, jj = i & 15;
        w2t[i] = f2bf(W2[jj * F_OUT + f]);
    }
    __syncthreads();

    int grp = t >> 2, l = t & 3;
    int n = n0 + grp;
    if (n < N_PER) {
        float di = dis2G[nbase + n];
        float4 pv = {0.f, 0.f, 0.f, 0.f};
        if (di != 0.f) {
            int cr = crG[nbase + n];
            int c4 = ((cr >> 16) + 3) & ~3;
            const unsigned short* cp = cg + (cr & 0xFFFF);
            float4 a0 = {0,0,0,0}, a1 = a0, a2 = a0, a3 = a0;
            for (int k = 0; k < c4; k += 4) {
                uint2 wv = *(const uint2*)(cp + k);
                int s0 = wv.x & 0xFFFF, s1 = wv.x >> 16, s2 = wv.y & 0xFFFF, s3 = wv.y >> 16;
                float4 v0 = *(const float4*)(hG + ((size_t)(nbase + s0) << 4) + 4 * l);
                float4 v1 = *(const float4*)(hG + ((size_t)(nbase + s1) << 4) + 4 * l);
                float4 v2 = *(const float4*)(hG + ((size_t)(nbase + s2) << 4) + 4 * l);
                float4 v3 = *(const float4*)(hG + ((size_t)(nbase + s3) << 4) + 4 * l);
                float w0 = wsrcl[s0], w1 = wsrcl[s1], w2 = wsrcl[s2], w3 = wsrcl[s3];
                a0.x = fmaf(v0.x, w0, a0.x); a0.y = fmaf(v0.y, w0, a0.y); a0.z = fmaf(v0.z, w0, a0.z); a0.w = fmaf(v0.w, w0, a0.w);
                a1.x = fmaf(v1.x, w1, a1.x); a1.y = fmaf(v1.y, w1, a1.y); a1.z = fmaf(v1.z, w1, a1.z); a1.w = fmaf(v1.w, w1, a1.w);
                a2.x = fmaf(v2.x, w2, a2.x); a2.y = fmaf(v2.y, w2, a2.y); a2.z = fmaf(v2.z, w2, a2.z); a2.w = fmaf(v2.w, w2, a2.w);
                a3.x = fmaf(v3.x, w3, a3.x); a3.y = fmaf(v3.y, w3, a3.y); a3.z = fmaf(v3.z, w3, a3.z); a3.w = fmaf(v3.w, w3, a3.w);
            }
            add4(a0, a1); add4(a2, a3); add4(a0, a2);
            float wn = wsrcl[n];
            float4 hs = *(const float4*)(hG + ((size_t)(nbase + n) << 4) + 4 * l);
            pv.x = di * fmaf(hs.x, wn, a0.x);
            pv.y = di * fmaf(hs.y, wn, a0.y);
            pv.z = di * fmaf(hs.z, wn, a0.z);
            pv.w = di * fmaf(hs.w, wn, a0.w);
        }
        unsigned int pk0 = (unsigned int)f2bf(pv.x) | ((unsigned int)f2bf(pv.y) << 16);
        unsigned int pk1 = (unsigned int)f2bf(pv.z) | ((unsigned int)f2bf(pv.w) << 16);
        *(unsigned int*)(fbf + grp * F_MID + 4 * l) = pk0;
        *(unsigned int*)(fbf + grp * F_MID + 4 * l + 2) = pk1;
        if (l == 0) mskl[grp] = mskG[nbase + n];
    } else {
        *(unsigned int*)(fbf + grp * F_MID + 4 * l) = 0u;
        *(unsigned int*)(fbf + grp * F_MID + 4 * l + 2) = 0u;
        if (l == 0) mskl[grp] = 0.f;
    }
    __syncthreads();

    // ---- (128x16)@(16x256) MFMA over this chunk, masked col-sums -> atomicAdd ----
    {
        int wave = t >> 6, lane = t & 63;
        int q = lane >> 4, fl = lane & 15;
        int c0 = 32 * wave + fl, c1 = c0 + 16;
        float b2f0 = b2[c0], b2f1 = b2[c1];
        short8 bfrag0 = {0,0,0,0,0,0,0,0}, bfrag1 = bfrag0;
        if (q < 2) {
            bfrag0 = *(const short8*)(w2t + c0 * F_MID + q * 8);
            bfrag1 = *(const short8*)(w2t + c1 * F_MID + q * 8);
        }
        floatx4 zero = {0.f, 0.f, 0.f, 0.f};
        float acc0 = 0.f, acc1 = 0.f;
        for (int tile = 0; tile < CHN / 16; tile++) {
            short8 afrag = {0,0,0,0,0,0,0,0};
            int na = tile * 16 + fl;
            if (q < 2)
                afrag = *(const short8*)(fbf + na * F_MID + q * 8);
            floatx4 d0 = __builtin_amdgcn_mfma_f32_16x16x32_bf16(afrag, bfrag0, zero, 0, 0, 0);
            floatx4 d1 = __builtin_amdgcn_mfma_f32_16x16x32_bf16(afrag, bfrag1, zero, 0, 0, 0);
#pragma unroll
            for (int r = 0; r < 4; r++) {
                int nd = tile * 16 + q * 4 + r;
                float m = mskl[nd];
                acc0 += m * fmaxf(d0[r] + b2f0, 0.f);
                acc1 += m * fmaxf(d1[r] + b2f1, 0.f);
            }
        }
        acc0 += __shfl_xor(acc0, 16); acc0 += __shfl_xor(acc0, 32);
        acc1 += __shfl_xor(acc1, 16); acc1 += __shfl_xor(acc1, 32);
        if (lane < 16) {
            atomicAdd(&out[g * F_OUT + c0], acc0 * (1.0f / (float)K_TOP));
            atomicAdd(&out[g * F_OUT + c1], acc1 * (1.0f / (float)K_TOP));
        }
    }
}

extern "C" void kernel_launch(void* const* d_in, const int* in_sizes, int n_in,
                              void* d_out, int out_size, void* d_ws, size_t ws_size,
                              hipStream_t stream) {
    const float* x      = (const float*)d_in[0];
    const int*   ei     = (const int*)d_in[1];
    const float* W1     = (const float*)d_in[3];
    const float* b1     = (const float*)d_in[4];
    const float* w_rel  = (const float*)d_in[5];
    const float* b_rel  = (const float*)d_in[6];
    const float* w_root = (const float*)d_in[7];
    const float* W2     = (const float*)d_in[8];
    const float* b2     = (const float*)d_in[9];
    float* out = (float*)d_out;

    char* ws = (char*)d_ws;
    size_t o = 0;
    auto nxt = [&](size_t bytes) { void* p = ws + o; o += (bytes + 255) & ~(size_t)255; return p; };
    unsigned short* csr = (unsigned short*)nxt((size_t)NG * EPGP * sizeof(unsigned short));
    int*   crG   = (int*)nxt((size_t)N_NODES * sizeof(int));
    float* dis1G = (float*)nxt((size_t)N_NODES * sizeof(float));
    float* xw1   = (float*)nxt(((size_t)N_NODES + 1) * F_MID * sizeof(float));
    float* hG    = (float*)nxt(((size_t)N_NODES + 1) * F_MID * sizeof(float));
    float* hwG   = (float*)nxt((size_t)N_NODES * sizeof(float));
    float* hroG  = (float*)nxt((size_t)N_NODES * sizeof(float));
    float* mskG  = (float*)nxt((size_t)N_NODES * sizeof(float));
    float* dis2G = (float*)nxt((size_t)N_NODES * sizeof(float));
    float* wsrcG = (float*)nxt((size_t)N_NODES * sizeof(float));

    int gemm_blocks = (N_NODES + 63) / 64;
    k_front<<<NG + gemm_blocks, 1024, 0, stream>>>(x, W1, ei, csr, crG, dis1G, xw1);
    k_conv1<<<NG * NCH, 512, 0, stream>>>(csr, crG, dis1G, xw1, b1, w_rel, w_root, hG, hwG, hroG);
    k_mid<<<NG, 1024, 0, stream>>>(csr, crG, hwG, hroG, b_rel, mskG, dis2G, wsrcG, out);
    k_conv2<<<NG * NCH, 512, 0, stream>>>(csr, crG, hG, wsrcG, dis2G, mskG, W2, b2, out);
}